// Round 8
// baseline (1015.422 us; speedup 1.0000x reference)
//
#include <hip/hip_runtime.h>
#include <math.h>

// DeepGCN layer, round 8: atomic-free CSR via LDS counting sort + bucket gather.
//   k_hist:    LDS histogram of dst>>6 per edge-chunk -> cnt[blk][NB]
//   k_scan1:   per-bucket exclusive scan over blocks (in-place) + totals
//   k_scan2:   block scan of totals -> bucketStart[NB+1]
//   k_scatter: LDS cursors; eb[pos] = (src<<6)|(dst&63), frontier-contiguous
//   k_deg:     per-bucket LDS count of dst&63 -> dinv
//   k_prep:    blocks 0..71 pack weights; rest: hs = f16(dinv_n*gelu(LN1(nf)))
//   k_bgather: block per bucket; LDS acc[64][128] f32; ds_add_f32 accumulate;
//              epilogue: aggh = f16(dinv_d * (acc + hs_self))
//   k_ffn:     LDS-staged aggh -> conv MFMA -> +nf -> LN2 -> stage1 MFMA+gelu
//              -> stage2 MFMA -> LDS round-trip -> coalesced residual epilogue
// MFMA 16x16x32 f16 layouts (m89/m101):
//   A[m = lane&15][k = (lane>>4)*8 + j]   (half8)
//   B[k = (lane>>4)*8 + j][n = lane&15]
//   D[m = (lane>>4)*4 + r][n = lane&15]   (float4)
// N = 100000 (multiple of 32), E = 1000000. MAXNB = 2048 (N <= 131072).

typedef _Float16 half8  __attribute__((ext_vector_type(8)));
typedef _Float16 half2v __attribute__((ext_vector_type(2)));
typedef __fp16   fp16x2 __attribute__((ext_vector_type(2)));
typedef float    floatx4 __attribute__((ext_vector_type(4)));

#define SBLK 128   // hist/scatter blocks

// tanh-form GELU: x*sigmoid(1.595769*(x+0.044715 x^3)); max abs err ~1e-3
__device__ __forceinline__ float gelu_f(float x){
  float x2 = x*x;
  float z  = x*(1.5957691216f + 0.07135481283f*x2);
  float e  = __expf(-z);
  return x * __builtin_amdgcn_rcpf(1.0f + e);
}
__device__ __forceinline__ unsigned pk16(float a, float b){   // 2x f32 -> packed f16 (RTZ)
  fp16x2 h = __builtin_amdgcn_cvt_pkrtz(a, b);
  return __builtin_bit_cast(unsigned, h);
}
__device__ __forceinline__ float wave_reduce_sum(float v){
  #pragma unroll
  for (int off = 32; off > 0; off >>= 1) v += __shfl_xor(v, off, 64);
  return v;
}

// ---------------- counting-sort CSR build ----------------
__global__ __launch_bounds__(256) void k_hist(const int* __restrict__ ei, int* __restrict__ cnt,
                                              int E, int NB, int ESB){
  __shared__ int h[2048];
  int t = threadIdx.x;
  for (int i = t; i < NB; i += 256) h[i] = 0;
  __syncthreads();
  int e0 = blockIdx.x * ESB;
  int e1 = min(E, e0 + ESB);
  for (int e = e0 + t; e < e1; e += 256)
    atomicAdd(&h[ei[E + e] >> 6], 1);
  __syncthreads();
  for (int i = t; i < NB; i += 256) cnt[(size_t)blockIdx.x * NB + i] = h[i];
}

// per-bucket exclusive scan over blocks (in place); totals out
__global__ void k_scan1(int* __restrict__ cnt, int* __restrict__ total, int NB, int nblk){
  int b = blockIdx.x*256 + threadIdx.x;
  if (b >= NB) return;
  int run = 0;
  for (int blk = 0; blk < nblk; blk++){
    int c = cnt[(size_t)blk*NB + b];
    cnt[(size_t)blk*NB + b] = run;
    run += c;
  }
  total[b] = run;
}

// single-block scan of totals -> bucketStart[NB+1]
__global__ __launch_bounds__(256) void k_scan2(const int* __restrict__ total,
                                               int* __restrict__ bucketStart, int NB){
  __shared__ int wsum[4];
  int t = threadIdx.x, w = t >> 6, l = t & 63;
  int vals[8];
  int sum = 0;
  #pragma unroll
  for (int j = 0; j < 8; j++){
    int idx = t*8 + j;
    vals[j] = (idx < NB) ? total[idx] : 0;
    sum += vals[j];
  }
  int x = sum;
  #pragma unroll
  for (int off = 1; off < 64; off <<= 1){
    int y = __shfl_up(x, off);
    if (l >= off) x += y;
  }
  if (l == 63) wsum[w] = x;
  __syncthreads();
  if (t == 0){
    int s = 0;
    #pragma unroll
    for (int i = 0; i < 4; i++){ int c = wsum[i]; wsum[i] = s; s += c; }
  }
  __syncthreads();
  int run = wsum[w] + x - sum;   // exclusive prefix for this thread's chunk
  #pragma unroll
  for (int j = 0; j < 8; j++){
    int idx = t*8 + j;
    if (idx < NB) bucketStart[idx] = run;
    run += vals[j];
  }
  if (t == 255) bucketStart[NB] = run;   // == E
}

__global__ __launch_bounds__(256) void k_scatter(const int* __restrict__ ei,
    const int* __restrict__ cnt, const int* __restrict__ bucketStart,
    int* __restrict__ eb, int E, int NB, int ESB){
  __shared__ int cur[2048];
  int t = threadIdx.x;
  for (int i = t; i < NB; i += 256)
    cur[i] = bucketStart[i] + cnt[(size_t)blockIdx.x*NB + i];
  __syncthreads();
  int e0 = blockIdx.x*ESB, e1 = min(E, e0 + ESB);
  for (int e = e0 + t; e < e1; e += 256){
    int s = ei[e], d = ei[E + e];
    int pos = atomicAdd(&cur[d >> 6], 1);
    eb[pos] = (s << 6) | (d & 63);
  }
}

// per-bucket degree -> dinv
__global__ __launch_bounds__(64) void k_deg(const int* __restrict__ eb,
    const int* __restrict__ bucketStart, float* __restrict__ dinv, int N){
  __shared__ int c[64];
  int b = blockIdx.x, t = threadIdx.x;
  c[t] = 0;
  __syncthreads();
  int s0 = bucketStart[b], s1 = bucketStart[b+1];
  for (int e = s0 + t; e < s1; e += 64) atomicAdd(&c[eb[e] & 63], 1);
  __syncthreads();
  int node = (b << 6) + t;
  if (node < N) dinv[node] = rsqrtf((float)c[t] + 1.0f);
}

// ---------------- k_prep: weight pack (blocks 0..71) + scaled LN1/gelu ----------------
__global__ __launch_bounds__(256) void k_prep(
    const float* __restrict__ Wc, const float* __restrict__ W1, const float* __restrict__ W2,
    _Float16* __restrict__ Wcp, _Float16* __restrict__ W1p, _Float16* __restrict__ W2p,
    const float* __restrict__ nf, const float* __restrict__ g, const float* __restrict__ b,
    const float* __restrict__ dinv, _Float16* __restrict__ hs)
{
  int bid = blockIdx.x;
  if (bid < 72){
    int id = bid*256 + threadIdx.x;   // 18432 total
    const float* W; _Float16* P; int K, Nc, base;
    if (id < 2048)            { W = Wc; P = Wcp; K = 128; Nc = 128; base = id; }
    else if (id < 2048+8192)  { W = W1; P = W1p; K = 128; Nc = 512; base = id - 2048; }
    else                      { W = W2; P = W2p; K = 512; Nc = 128; base = id - 10240; }
    int lane = base & 63;
    int nkb  = K >> 5;
    int kb   = (base >> 6) % nkb;
    int tile = base / (nkb << 6);
    int col  = (tile << 4) + (lane & 15);
    int k0   = (kb << 5) + ((lane >> 4) << 3);
    _Float16 v[8];
    #pragma unroll
    for (int j = 0; j < 8; j++) v[j] = (_Float16)W[(size_t)(k0 + j)*Nc + col];
    *(half8*)&P[(size_t)base * 8] = *(const half8*)v;
  } else {
    int w = threadIdx.x >> 6, l = threadIdx.x & 63;
    int node = (bid - 72)*4 + w;
    float2 x = *(const float2*)&nf[(size_t)node*128 + 2*l];
    float mu = wave_reduce_sum(x.x + x.y) * 0.0078125f;
    float d0 = x.x - mu, d1 = x.y - mu;
    float var = wave_reduce_sum(d0*d0 + d1*d1) * 0.0078125f;
    float rs = rsqrtf(var + 1e-5f);
    float dn = dinv[node];
    float y0 = dn * gelu_f(d0*rs*g[2*l]   + b[2*l]);
    float y1 = dn * gelu_f(d1*rs*g[2*l+1] + b[2*l+1]);
    *(unsigned*)&hs[(size_t)node*128 + 2*l] = pk16(y0, y1);
  }
}

// ---------------- bucket gather: LDS accumulate ----------------
__global__ __launch_bounds__(256) void k_bgather(const _Float16* __restrict__ hs,
    const int* __restrict__ eb, const int* __restrict__ bucketStart,
    const float* __restrict__ dinv, _Float16* __restrict__ aggh, int N)
{
  __shared__ float acc[64*128];   // 32 KB
  int t = threadIdx.x, w = t >> 6, l = t & 63;
  int b = blockIdx.x;
  #pragma unroll
  for (int j = 0; j < 32; j++) acc[t + 256*j] = 0.f;
  __syncthreads();
  int s0 = bucketStart[b], s1 = bucketStart[b+1];
  for (int base = s0 + (w << 6); base < s1; base += 256){
    int idx = base + l;
    int pv = (idx < s1) ? eb[idx] : 0;
    int cnt = min(64, s1 - base);
    for (int i = 0; i < cnt; i++){
      int v = __shfl(pv, i);
      int row = v >> 6, ld = v & 63;
      // lane l owns cols {l, l+64}; ld is wave-uniform -> LDS banks 2-way (free)
      float x0 = (float)hs[(size_t)row*128 + l];
      float x1 = (float)hs[(size_t)row*128 + 64 + l];
      atomicAdd(&acc[(ld << 7) + l], x0);
      atomicAdd(&acc[(ld << 7) + 64 + l], x1);
    }
  }
  __syncthreads();
  int n0 = b << 6;
  #pragma unroll
  for (int q = 0; q < 16; q++){
    int m = (w << 4) + q;
    int node = n0 + m;
    if (node < N){
      float dn = dinv[node];
      float v0 = acc[(m << 7) + l]      + (float)hs[(size_t)node*128 + l];
      float v1 = acc[(m << 7) + 64 + l] + (float)hs[(size_t)node*128 + 64 + l];
      aggh[(size_t)node*128 + l]      = (_Float16)(dn * v0);
      aggh[(size_t)node*128 + 64 + l] = (_Float16)(dn * v1);
    }
  }
}

// ---------------- fused conv-GEMM + LN2 + FFN, all coalesced ----------------
// LDS map (u_s, 33280 B):
//   [0, 4352)      shorts: F16 conv/LN2 result, stride 136 (f16)
//   [4352, 8704)   shorts: aggh stage, stride 136 (f16)
//   t_s: full u_s, stride 520 (f16)            [after F16 frags consumed]
//   fs : full u_s as float, stride 132 (fp32)  [after t_s consumed]
__global__ __launch_bounds__(256) void k_ffn(
    const float* __restrict__ nf, const _Float16* __restrict__ aggh,
    const _Float16* __restrict__ Wcp, const float* __restrict__ bc,
    const float* __restrict__ g2, const float* __restrict__ bl2,
    const _Float16* __restrict__ W1p, const float* __restrict__ b1,
    const _Float16* __restrict__ W2p, const float* __restrict__ b2,
    float* __restrict__ out, int N)
{
  __shared__ __align__(16) unsigned short u_s[32*520];
  int t = threadIdx.x, w = t >> 6, l = t & 63;
  int nb = blockIdx.x << 5;
  int quad = l >> 4, ln16 = l & 15;

  // ---- A0: stage aggh coalesced -> LDS stride-136 region
  {
    int m = t >> 3, c0 = (t & 7) << 4;
    const uint4* src = (const uint4*)&aggh[(size_t)(nb + m)*128 + c0];
    uint4 v0 = src[0], v1 = src[1];
    uint4* dst = (uint4*)&u_s[4352 + m*136 + c0];
    dst[0] = v0; dst[1] = v1;
  }
  __syncthreads();

  // ---- A: conv MFMA; write (aggW + bc) f16 -> F16 region
  {
    half8 ag[2][4];
    #pragma unroll
    for (int mt = 0; mt < 2; mt++)
      #pragma unroll
      for (int kb = 0; kb < 4; kb++)
        ag[mt][kb] = *(const half8*)&u_s[4352 + ((mt << 4) + ln16)*136 + (kb << 5) + (quad << 3)];
    const half8* Wp8 = (const half8*)Wcp;
    #pragma unroll
    for (int nt = 0; nt < 2; nt++){
      int tile = (w << 1) + nt;
      half8 bf[4];
      #pragma unroll
      for (int kb = 0; kb < 4; kb++) bf[kb] = Wp8[(size_t)((tile << 2) + kb)*64 + l];
      floatx4 acc0 = {0.f,0.f,0.f,0.f}, acc1 = {0.f,0.f,0.f,0.f};
      #pragma unroll
      for (int kb = 0; kb < 4; kb++){
        acc0 = __builtin_amdgcn_mfma_f32_16x16x32_f16(ag[0][kb], bf[kb], acc0, 0, 0, 0);
        acc1 = __builtin_amdgcn_mfma_f32_16x16x32_f16(ag[1][kb], bf[kb], acc1, 0, 0, 0);
      }
      int col = (tile << 4) + ln16;
      float bcv = bc[col];
      #pragma unroll
      for (int r = 0; r < 4; r++){
        int m0 = (quad << 2) + r;
        *(_Float16*)&u_s[m0*136 + col]        = (_Float16)(acc0[r] + bcv);
        *(_Float16*)&u_s[(m0 + 16)*136 + col] = (_Float16)(acc1[r] + bcv);
      }
    }
  }
  __syncthreads();

  // ---- B: LN2 on (F16 + nf), coalesced; nf kept in registers
  float2 nfr[8];
  #pragma unroll
  for (int q = 0; q < 8; q++){
    int m = (w << 3) + q;
    unsigned pu = *(unsigned*)&u_s[m*136 + 2*l];
    half2v hp = __builtin_bit_cast(half2v, pu);
    nfr[q] = *(const float2*)&nf[(size_t)(nb + m)*128 + 2*l];
    float x0 = (float)hp.x + nfr[q].x;
    float x1 = (float)hp.y + nfr[q].y;
    float mu = wave_reduce_sum(x0 + x1) * 0.0078125f;
    float d0 = x0 - mu, d1 = x1 - mu;
    float var = wave_reduce_sum(d0*d0 + d1*d1) * 0.0078125f;
    float rs = rsqrtf(var + 1e-5f);
    float y0 = d0*rs*g2[2*l]   + bl2[2*l];
    float y1 = d1*rs*g2[2*l+1] + bl2[2*l+1];
    *(unsigned*)&u_s[m*136 + 2*l] = pk16(y0, y1);
  }
  __syncthreads();

  // A-fragments into registers; F16 region dead afterwards
  half8 a[2][4];
  #pragma unroll
  for (int mt = 0; mt < 2; mt++)
    #pragma unroll
    for (int kb = 0; kb < 4; kb++)
      a[mt][kb] = *(const half8*)&u_s[((mt << 4) + ln16)*136 + (kb << 5) + (quad << 3)];
  __syncthreads();

  // ---- stage 1: t = gelu(f @ W1 + b1) -> t_s (stride 520). Wave w: N-tiles [8w, 8w+8).
  {
    const half8* Wp8 = (const half8*)W1p;
    #pragma unroll
    for (int nt = 0; nt < 8; nt++){
      int tile = (w << 3) + nt;
      half8 bf[4];
      #pragma unroll
      for (int kb = 0; kb < 4; kb++) bf[kb] = Wp8[(size_t)((tile << 2) + kb)*64 + l];
      floatx4 acc0 = {0.f,0.f,0.f,0.f}, acc1 = {0.f,0.f,0.f,0.f};
      #pragma unroll
      for (int kb = 0; kb < 4; kb++){
        acc0 = __builtin_amdgcn_mfma_f32_16x16x32_f16(a[0][kb], bf[kb], acc0, 0, 0, 0);
        acc1 = __builtin_amdgcn_mfma_f32_16x16x32_f16(a[1][kb], bf[kb], acc1, 0, 0, 0);
      }
      int col = (tile << 4) + ln16;
      float bv = b1[col];
      #pragma unroll
      for (int r = 0; r < 4; r++){
        *(_Float16*)&u_s[((quad << 2) + r)*520 + col]      = (_Float16)gelu_f(acc0[r] + bv);
        *(_Float16*)&u_s[(16 + (quad << 2) + r)*520 + col] = (_Float16)gelu_f(acc1[r] + bv);
      }
    }
  }
  __syncthreads();

  // ---- stage 2: f2 = gelu(t @ W2 + b2). Wave w: N-tiles {2w, 2w+1}.
  floatx4 acc00 = {0.f,0.f,0.f,0.f}, acc01 = {0.f,0.f,0.f,0.f};
  floatx4 acc10 = {0.f,0.f,0.f,0.f}, acc11 = {0.f,0.f,0.f,0.f};
  int tile0 = (w << 1), tile1 = tile0 + 1;
  {
    const half8* Wp8 = (const half8*)W2p;
    for (int kb = 0; kb < 16; kb++){
      half8 a0 = *(const half8*)&u_s[ln16*520        + (kb << 5) + (quad << 3)];
      half8 a1 = *(const half8*)&u_s[(16 + ln16)*520 + (kb << 5) + (quad << 3)];
      half8 b0  = Wp8[(size_t)((tile0 << 4) + kb)*64 + l];
      half8 b1v = Wp8[(size_t)((tile1 << 4) + kb)*64 + l];
      acc00 = __builtin_amdgcn_mfma_f32_16x16x32_f16(a0, b0,  acc00, 0, 0, 0);
      acc01 = __builtin_amdgcn_mfma_f32_16x16x32_f16(a0, b1v, acc01, 0, 0, 0);
      acc10 = __builtin_amdgcn_mfma_f32_16x16x32_f16(a1, b0,  acc10, 0, 0, 0);
      acc11 = __builtin_amdgcn_mfma_f32_16x16x32_f16(a1, b1v, acc11, 0, 0, 0);
    }
  }
  __syncthreads();   // all t_s reads done; u_s reusable as fp32

  // ---- write f2 to LDS (fp32, stride 132), D-layout
  {
    float* fs = (float*)u_s;
    int col0 = (tile0 << 4) + ln16, col1 = (tile1 << 4) + ln16;
    float bv0 = b2[col0], bv1 = b2[col1];
    #pragma unroll
    for (int r = 0; r < 4; r++){
      int m0 = (quad << 2) + r;
      fs[m0*132 + col0]        = gelu_f(acc00[r] + bv0);
      fs[m0*132 + col1]        = gelu_f(acc01[r] + bv1);
      fs[(m0 + 16)*132 + col0] = gelu_f(acc10[r] + bv0);
      fs[(m0 + 16)*132 + col1] = gelu_f(acc11[r] + bv1);
    }
  }
  __syncthreads();

  // ---- coalesced residual epilogue: out = nf + f2
  {
    const float* fs = (const float*)u_s;
    #pragma unroll
    for (int q = 0; q < 8; q++){
      int m = (w << 3) + q;
      float2 o;
      o.x = nfr[q].x + fs[m*132 + 2*l];
      o.y = nfr[q].y + fs[m*132 + 2*l + 1];
      *(float2*)&out[(size_t)(nb + m)*128 + 2*l] = o;
    }
  }
}

extern "C" void kernel_launch(void* const* d_in, const int* in_sizes, int n_in,
                              void* d_out, int out_size, void* d_ws, size_t ws_size,
                              hipStream_t stream) {
  const float* nf   = (const float*)d_in[0];
  const int*   ei   = (const int*)  d_in[1];
  const float* ln1g = (const float*)d_in[3];
  const float* ln1b = (const float*)d_in[4];
  const float* Wc   = (const float*)d_in[5];
  const float* bc   = (const float*)d_in[6];
  const float* ln2g = (const float*)d_in[7];
  const float* ln2b = (const float*)d_in[8];
  const float* W1   = (const float*)d_in[9];
  const float* b1   = (const float*)d_in[10];
  const float* W2   = (const float*)d_in[11];
  const float* b2   = (const float*)d_in[12];
  float* out = (float*)d_out;

  int N = in_sizes[0] / 128;
  int E = in_sizes[1] / 2;
  int NB  = (N + 63) >> 6;            // 1563
  int ESB = (E + SBLK - 1) / SBLK;    // 7813

  char* ws = (char*)d_ws;
  _Float16* hs   = (_Float16*)ws;                              // [N,128] f16
  _Float16* aggh = (_Float16*)(ws + (size_t)N*128*2);          // [N,128] f16
  char* p = ws + (size_t)N*128*4;
  p = (char*)(((size_t)p + 15) & ~(size_t)15);
  int*   cnt         = (int*)p;   p += (size_t)SBLK*NB*4;
  int*   total       = (int*)p;   p += (size_t)NB*4;
  int*   bucketStart = (int*)p;   p += (size_t)(NB+1)*4;
  float* dinv        = (float*)p; p += (size_t)N*4;
  int*   eb          = (int*)p;   p += (size_t)E*4;
  p = (char*)(((size_t)p + 15) & ~(size_t)15);
  _Float16* Wcp = (_Float16*)p; p += (size_t)2048*8*2;    // 32 KB
  _Float16* W1p = (_Float16*)p; p += (size_t)8192*8*2;    // 128 KB
  _Float16* W2p = (_Float16*)p; p += (size_t)8192*8*2;    // 128 KB

  k_hist   <<<SBLK, 256, 0, stream>>>(ei, cnt, E, NB, ESB);
  k_scan1  <<<(NB+255)/256, 256, 0, stream>>>(cnt, total, NB, SBLK);
  k_scan2  <<<1, 256, 0, stream>>>(total, bucketStart, NB);
  k_scatter<<<SBLK, 256, 0, stream>>>(ei, cnt, bucketStart, eb, E, NB, ESB);
  k_deg    <<<NB, 64, 0, stream>>>(eb, bucketStart, dinv, N);

  k_prep   <<<72 + N/4, 256, 0, stream>>>(Wc, W1, W2, Wcp, W1p, W2p, nf, ln1g, ln1b, dinv, hs);
  k_bgather<<<NB, 256, 0, stream>>>(hs, eb, bucketStart, dinv, aggh, N);
  k_ffn    <<<N/32, 256, 0, stream>>>(nf, aggh, Wcp, bc, ln2g, ln2b, W1p, b1, W2p, b2, out, N);
}

// Round 9
// 287.985 us; speedup vs baseline: 3.5260x; 3.5260x over previous
//
#include <hip/hip_runtime.h>
#include <math.h>

// DeepGCN layer, round 9: two-level LDS counting sort -> full per-dst CSR,
// parallel 8-slot gather (round-7 style), fused MFMA FFN.
//   k_hist:   per-chunk LDS histogram of dst>>6 -> cnt[blk][NB]
//   k_scanB:  block b scans cnt[*][b] over 128 chunks (1563 blocks)
//   k_scan2:  single-block scan of totals -> bucketStart[NB+1]
//   k_scatter: LDS cursors; eb[pos] = (src<<6)|(dst&63)  (bucket-sorted)
//   k_sort2:  per-bucket LDS sort by dst&63 -> eSrc (dst-sorted), row_start,
//             incount, dinv  (all writes contiguous per bucket)
//   k_prep:   blocks 0..71 pack weights; rest: hs = f16(dinv_n*gelu(LN1(nf)))
//   k_gather: per-node, 8 edge-slots/wave, uint4 hs rows, shuffle-reduce
//   k_ffn:    LDS-staged aggh -> conv MFMA -> +nf -> LN2 -> stage1 MFMA+gelu
//             -> stage2 MFMA -> LDS round-trip -> coalesced residual epilogue
// MFMA 16x16x32 f16 layouts (m89/m101):
//   A[m = lane&15][k = (lane>>4)*8 + j]   (half8)
//   B[k = (lane>>4)*8 + j][n = lane&15]
//   D[m = (lane>>4)*4 + r][n = lane&15]   (float4)
// N = 100000 (multiple of 32), E = 1000000. NB <= 2048.

typedef _Float16 half8  __attribute__((ext_vector_type(8)));
typedef _Float16 half2v __attribute__((ext_vector_type(2)));
typedef __fp16   fp16x2 __attribute__((ext_vector_type(2)));
typedef float    floatx4 __attribute__((ext_vector_type(4)));

#define SBLK 128   // hist/scatter edge-chunks

__device__ __forceinline__ float gelu_f(float x){
  float x2 = x*x;
  float z  = x*(1.5957691216f + 0.07135481283f*x2);
  float e  = __expf(-z);
  return x * __builtin_amdgcn_rcpf(1.0f + e);
}
__device__ __forceinline__ unsigned pk16(float a, float b){
  fp16x2 h = __builtin_amdgcn_cvt_pkrtz(a, b);
  return __builtin_bit_cast(unsigned, h);
}
__device__ __forceinline__ float wave_reduce_sum(float v){
  #pragma unroll
  for (int off = 32; off > 0; off >>= 1) v += __shfl_xor(v, off, 64);
  return v;
}

// ---------------- two-level counting sort ----------------
__global__ __launch_bounds__(256) void k_hist(const int* __restrict__ ei, int* __restrict__ cnt,
                                              int E, int NB, int ESB){
  __shared__ int h[2048];
  int t = threadIdx.x;
  for (int i = t; i < NB; i += 256) h[i] = 0;
  __syncthreads();
  int e0 = blockIdx.x * ESB;
  int e1 = min(E, e0 + ESB);
  for (int e = e0 + t; e < e1; e += 256)
    atomicAdd(&h[ei[E + e] >> 6], 1);
  __syncthreads();
  for (int i = t; i < NB; i += 256) cnt[(size_t)blockIdx.x * NB + i] = h[i];
}

// block b: exclusive scan of cnt[0..SBLK)[b]; total -> total[b]
__global__ __launch_bounds__(128) void k_scanB(int* __restrict__ cnt, int* __restrict__ total,
                                               int NB){
  __shared__ int w0sum;
  int b = blockIdx.x;
  int t = threadIdx.x, l = t & 63, w = t >> 6;
  int v = cnt[(size_t)t*NB + b];
  int x = v;
  #pragma unroll
  for (int off = 1; off < 64; off <<= 1){
    int y = __shfl_up(x, off);
    if (l >= off) x += y;
  }
  if (w == 0 && l == 63) w0sum = x;
  __syncthreads();
  int ex = x - v + (w ? w0sum : 0);
  cnt[(size_t)t*NB + b] = ex;
  if (t == 127) total[b] = ex + v;
}

// single-block scan of totals -> bucketStart[NB+1]
__global__ __launch_bounds__(256) void k_scan2(const int* __restrict__ total,
                                               int* __restrict__ bucketStart, int NB){
  __shared__ int wsum[4];
  int t = threadIdx.x, w = t >> 6, l = t & 63;
  int vals[8];
  int sum = 0;
  #pragma unroll
  for (int j = 0; j < 8; j++){
    int idx = t*8 + j;
    vals[j] = (idx < NB) ? total[idx] : 0;
    sum += vals[j];
  }
  int x = sum;
  #pragma unroll
  for (int off = 1; off < 64; off <<= 1){
    int y = __shfl_up(x, off);
    if (l >= off) x += y;
  }
  if (l == 63) wsum[w] = x;
  __syncthreads();
  if (t == 0){
    int s = 0;
    #pragma unroll
    for (int i = 0; i < 4; i++){ int c = wsum[i]; wsum[i] = s; s += c; }
  }
  __syncthreads();
  int run = wsum[w] + x - sum;
  #pragma unroll
  for (int j = 0; j < 8; j++){
    int idx = t*8 + j;
    if (idx < NB) bucketStart[idx] = run;
    run += vals[j];
  }
  if (t == 255) bucketStart[NB] = run;   // == E
}

__global__ __launch_bounds__(256) void k_scatter(const int* __restrict__ ei,
    const int* __restrict__ cnt, const int* __restrict__ bucketStart,
    int* __restrict__ eb, int E, int NB, int ESB){
  __shared__ int cur[2048];
  int t = threadIdx.x;
  for (int i = t; i < NB; i += 256)
    cur[i] = bucketStart[i] + cnt[(size_t)blockIdx.x*NB + i];
  __syncthreads();
  int e0 = blockIdx.x*ESB, e1 = min(E, e0 + ESB);
  for (int e = e0 + t; e < e1; e += 256){
    int s = ei[e], d = ei[E + e];
    int pos = atomicAdd(&cur[d >> 6], 1);
    eb[pos] = (s << 6) | (d & 63);
  }
}

// per-bucket: sort by dst&63 -> eSrc; row_start/incount/dinv
__global__ __launch_bounds__(256) void k_sort2(const int* __restrict__ eb,
    const int* __restrict__ bucketStart, int* __restrict__ eSrc,
    int* __restrict__ row_start, int* __restrict__ incount,
    float* __restrict__ dinv, int N){
  __shared__ int hcnt[64];
  __shared__ int hcur[64];
  int b = blockIdx.x, t = threadIdx.x;
  if (t < 64) hcnt[t] = 0;
  __syncthreads();
  int s0 = bucketStart[b], s1 = bucketStart[b+1];
  for (int e = s0 + t; e < s1; e += 256) atomicAdd(&hcnt[eb[e] & 63], 1);
  __syncthreads();
  if (t < 64){
    int v = hcnt[t];
    int x = v;
    #pragma unroll
    for (int off = 1; off < 64; off <<= 1){
      int y = __shfl_up(x, off);
      if (t >= off) x += y;
    }
    int ex = x - v;
    hcur[t] = ex;
    int node = (b << 6) + t;
    if (node < N){
      row_start[node] = s0 + ex;
      incount[node]   = v;
      dinv[node]      = rsqrtf((float)v + 1.0f);
    }
  }
  __syncthreads();
  for (int e = s0 + t; e < s1; e += 256){
    int v = eb[e];
    int pos = atomicAdd(&hcur[v & 63], 1);
    eSrc[s0 + pos] = v >> 6;
  }
}

// ---------------- k_prep: weight pack (blocks 0..71) + scaled LN1/gelu ----------------
__global__ __launch_bounds__(256) void k_prep(
    const float* __restrict__ Wc, const float* __restrict__ W1, const float* __restrict__ W2,
    _Float16* __restrict__ Wcp, _Float16* __restrict__ W1p, _Float16* __restrict__ W2p,
    const float* __restrict__ nf, const float* __restrict__ g, const float* __restrict__ b,
    const float* __restrict__ dinv, _Float16* __restrict__ hs)
{
  int bid = blockIdx.x;
  if (bid < 72){
    int id = bid*256 + threadIdx.x;   // 18432 total
    const float* W; _Float16* P; int K, Nc, base;
    if (id < 2048)            { W = Wc; P = Wcp; K = 128; Nc = 128; base = id; }
    else if (id < 2048+8192)  { W = W1; P = W1p; K = 128; Nc = 512; base = id - 2048; }
    else                      { W = W2; P = W2p; K = 512; Nc = 128; base = id - 10240; }
    int lane = base & 63;
    int nkb  = K >> 5;
    int kb   = (base >> 6) % nkb;
    int tile = base / (nkb << 6);
    int col  = (tile << 4) + (lane & 15);
    int k0   = (kb << 5) + ((lane >> 4) << 3);
    _Float16 v[8];
    #pragma unroll
    for (int j = 0; j < 8; j++) v[j] = (_Float16)W[(size_t)(k0 + j)*Nc + col];
    *(half8*)&P[(size_t)base * 8] = *(const half8*)v;
  } else {
    int w = threadIdx.x >> 6, l = threadIdx.x & 63;
    int node = (bid - 72)*4 + w;
    float2 x = *(const float2*)&nf[(size_t)node*128 + 2*l];
    float mu = wave_reduce_sum(x.x + x.y) * 0.0078125f;
    float d0 = x.x - mu, d1 = x.y - mu;
    float var = wave_reduce_sum(d0*d0 + d1*d1) * 0.0078125f;
    float rs = rsqrtf(var + 1e-5f);
    float dn = dinv[node];
    float y0 = dn * gelu_f(d0*rs*g[2*l]   + b[2*l]);
    float y1 = dn * gelu_f(d1*rs*g[2*l+1] + b[2*l+1]);
    *(unsigned*)&hs[(size_t)node*128 + 2*l] = pk16(y0, y1);
  }
}

// ---------------- CSR gather over hs: 8 edge-slots per wave ----------------
__global__ __launch_bounds__(256) void k_gather(const _Float16* __restrict__ hs,
    const int* __restrict__ eSrc, const int* __restrict__ row_start,
    const int* __restrict__ incount, const float* __restrict__ dinv,
    _Float16* __restrict__ aggh, int N)
{
  int w = threadIdx.x >> 6, l = threadIdx.x & 63;
  int node = (blockIdx.x << 2) + w;
  int g  = l >> 3;     // edge slot 0..7
  int li = l & 7;      // 32B chunk: cols li*16 .. li*16+15
  float dn = dinv[node];
  int start = row_start[node], cnt = incount[node];
  float acc[16];
  #pragma unroll
  for (int i = 0; i < 16; i++) acc[i] = 0.f;
  // virtual edge 0 = self-loop (hs already carries dinv_src scaling)
  for (int e = g; e < cnt + 1; e += 8){
    int s = (e == 0) ? node : eSrc[start + e - 1];
    const uint4* hp = (const uint4*)&hs[(size_t)s*128 + (li << 4)];
    uint4 v0 = hp[0], v1 = hp[1];
    half2v p0 = __builtin_bit_cast(half2v, v0.x), p1 = __builtin_bit_cast(half2v, v0.y);
    half2v p2 = __builtin_bit_cast(half2v, v0.z), p3 = __builtin_bit_cast(half2v, v0.w);
    half2v p4 = __builtin_bit_cast(half2v, v1.x), p5 = __builtin_bit_cast(half2v, v1.y);
    half2v p6 = __builtin_bit_cast(half2v, v1.z), p7 = __builtin_bit_cast(half2v, v1.w);
    acc[0]  += (float)p0.x; acc[1]  += (float)p0.y;
    acc[2]  += (float)p1.x; acc[3]  += (float)p1.y;
    acc[4]  += (float)p2.x; acc[5]  += (float)p2.y;
    acc[6]  += (float)p3.x; acc[7]  += (float)p3.y;
    acc[8]  += (float)p4.x; acc[9]  += (float)p4.y;
    acc[10] += (float)p5.x; acc[11] += (float)p5.y;
    acc[12] += (float)p6.x; acc[13] += (float)p6.y;
    acc[14] += (float)p7.x; acc[15] += (float)p7.y;
  }
  #pragma unroll
  for (int i = 0; i < 16; i++){
    acc[i] += __shfl_xor(acc[i], 8);
    acc[i] += __shfl_xor(acc[i], 16);
    acc[i] += __shfl_xor(acc[i], 32);
  }
  if (l < 8){
    uint4 o0, o1;
    o0.x = pk16(dn*acc[0],  dn*acc[1]);  o0.y = pk16(dn*acc[2],  dn*acc[3]);
    o0.z = pk16(dn*acc[4],  dn*acc[5]);  o0.w = pk16(dn*acc[6],  dn*acc[7]);
    o1.x = pk16(dn*acc[8],  dn*acc[9]);  o1.y = pk16(dn*acc[10], dn*acc[11]);
    o1.z = pk16(dn*acc[12], dn*acc[13]); o1.w = pk16(dn*acc[14], dn*acc[15]);
    uint4* op = (uint4*)&aggh[(size_t)node*128 + (l << 4)];
    op[0] = o0; op[1] = o1;
  }
}

// ---------------- fused conv-GEMM + LN2 + FFN, all coalesced ----------------
__global__ __launch_bounds__(256) void k_ffn(
    const float* __restrict__ nf, const _Float16* __restrict__ aggh,
    const _Float16* __restrict__ Wcp, const float* __restrict__ bc,
    const float* __restrict__ g2, const float* __restrict__ bl2,
    const _Float16* __restrict__ W1p, const float* __restrict__ b1,
    const _Float16* __restrict__ W2p, const float* __restrict__ b2,
    float* __restrict__ out, int N)
{
  __shared__ __align__(16) unsigned short u_s[32*520];
  int t = threadIdx.x, w = t >> 6, l = t & 63;
  int nb = blockIdx.x << 5;
  int quad = l >> 4, ln16 = l & 15;

  // ---- A0: stage aggh coalesced -> LDS stride-136 region
  {
    int m = t >> 3, c0 = (t & 7) << 4;
    const uint4* src = (const uint4*)&aggh[(size_t)(nb + m)*128 + c0];
    uint4 v0 = src[0], v1 = src[1];
    uint4* dst = (uint4*)&u_s[4352 + m*136 + c0];
    dst[0] = v0; dst[1] = v1;
  }
  __syncthreads();

  // ---- A: conv MFMA; write (aggW + bc) f16 -> F16 region
  {
    half8 ag[2][4];
    #pragma unroll
    for (int mt = 0; mt < 2; mt++)
      #pragma unroll
      for (int kb = 0; kb < 4; kb++)
        ag[mt][kb] = *(const half8*)&u_s[4352 + ((mt << 4) + ln16)*136 + (kb << 5) + (quad << 3)];
    const half8* Wp8 = (const half8*)Wcp;
    #pragma unroll
    for (int nt = 0; nt < 2; nt++){
      int tile = (w << 1) + nt;
      half8 bf[4];
      #pragma unroll
      for (int kb = 0; kb < 4; kb++) bf[kb] = Wp8[(size_t)((tile << 2) + kb)*64 + l];
      floatx4 acc0 = {0.f,0.f,0.f,0.f}, acc1 = {0.f,0.f,0.f,0.f};
      #pragma unroll
      for (int kb = 0; kb < 4; kb++){
        acc0 = __builtin_amdgcn_mfma_f32_16x16x32_f16(ag[0][kb], bf[kb], acc0, 0, 0, 0);
        acc1 = __builtin_amdgcn_mfma_f32_16x16x32_f16(ag[1][kb], bf[kb], acc1, 0, 0, 0);
      }
      int col = (tile << 4) + ln16;
      float bcv = bc[col];
      #pragma unroll
      for (int r = 0; r < 4; r++){
        int m0 = (quad << 2) + r;
        *(_Float16*)&u_s[m0*136 + col]        = (_Float16)(acc0[r] + bcv);
        *(_Float16*)&u_s[(m0 + 16)*136 + col] = (_Float16)(acc1[r] + bcv);
      }
    }
  }
  __syncthreads();

  // ---- B: LN2 on (F16 + nf), coalesced; nf kept in registers
  float2 nfr[8];
  #pragma unroll
  for (int q = 0; q < 8; q++){
    int m = (w << 3) + q;
    unsigned pu = *(unsigned*)&u_s[m*136 + 2*l];
    half2v hp = __builtin_bit_cast(half2v, pu);
    nfr[q] = *(const float2*)&nf[(size_t)(nb + m)*128 + 2*l];
    float x0 = (float)hp.x + nfr[q].x;
    float x1 = (float)hp.y + nfr[q].y;
    float mu = wave_reduce_sum(x0 + x1) * 0.0078125f;
    float d0 = x0 - mu, d1 = x1 - mu;
    float var = wave_reduce_sum(d0*d0 + d1*d1) * 0.0078125f;
    float rs = rsqrtf(var + 1e-5f);
    float y0 = d0*rs*g2[2*l]   + bl2[2*l];
    float y1 = d1*rs*g2[2*l+1] + bl2[2*l+1];
    *(unsigned*)&u_s[m*136 + 2*l] = pk16(y0, y1);
  }
  __syncthreads();

  // A-fragments into registers; F16 region dead afterwards
  half8 a[2][4];
  #pragma unroll
  for (int mt = 0; mt < 2; mt++)
    #pragma unroll
    for (int kb = 0; kb < 4; kb++)
      a[mt][kb] = *(const half8*)&u_s[((mt << 4) + ln16)*136 + (kb << 5) + (quad << 3)];
  __syncthreads();

  // ---- stage 1: t = gelu(f @ W1 + b1) -> t_s (stride 520). Wave w: N-tiles [8w, 8w+8).
  {
    const half8* Wp8 = (const half8*)W1p;
    #pragma unroll
    for (int nt = 0; nt < 8; nt++){
      int tile = (w << 3) + nt;
      half8 bf[4];
      #pragma unroll
      for (int kb = 0; kb < 4; kb++) bf[kb] = Wp8[(size_t)((tile << 2) + kb)*64 + l];
      floatx4 acc0 = {0.f,0.f,0.f,0.f}, acc1 = {0.f,0.f,0.f,0.f};
      #pragma unroll
      for (int kb = 0; kb < 4; kb++){
        acc0 = __builtin_amdgcn_mfma_f32_16x16x32_f16(a[0][kb], bf[kb], acc0, 0, 0, 0);
        acc1 = __builtin_amdgcn_mfma_f32_16x16x32_f16(a[1][kb], bf[kb], acc1, 0, 0, 0);
      }
      int col = (tile << 4) + ln16;
      float bv = b1[col];
      #pragma unroll
      for (int r = 0; r < 4; r++){
        *(_Float16*)&u_s[((quad << 2) + r)*520 + col]      = (_Float16)gelu_f(acc0[r] + bv);
        *(_Float16*)&u_s[(16 + (quad << 2) + r)*520 + col] = (_Float16)gelu_f(acc1[r] + bv);
      }
    }
  }
  __syncthreads();

  // ---- stage 2: f2 = gelu(t @ W2 + b2). Wave w: N-tiles {2w, 2w+1}.
  floatx4 acc00 = {0.f,0.f,0.f,0.f}, acc01 = {0.f,0.f,0.f,0.f};
  floatx4 acc10 = {0.f,0.f,0.f,0.f}, acc11 = {0.f,0.f,0.f,0.f};
  int tile0 = (w << 1), tile1 = tile0 + 1;
  {
    const half8* Wp8 = (const half8*)W2p;
    for (int kb = 0; kb < 16; kb++){
      half8 a0 = *(const half8*)&u_s[ln16*520        + (kb << 5) + (quad << 3)];
      half8 a1 = *(const half8*)&u_s[(16 + ln16)*520 + (kb << 5) + (quad << 3)];
      half8 b0  = Wp8[(size_t)((tile0 << 4) + kb)*64 + l];
      half8 b1v = Wp8[(size_t)((tile1 << 4) + kb)*64 + l];
      acc00 = __builtin_amdgcn_mfma_f32_16x16x32_f16(a0, b0,  acc00, 0, 0, 0);
      acc01 = __builtin_amdgcn_mfma_f32_16x16x32_f16(a0, b1v, acc01, 0, 0, 0);
      acc10 = __builtin_amdgcn_mfma_f32_16x16x32_f16(a1, b0,  acc10, 0, 0, 0);
      acc11 = __builtin_amdgcn_mfma_f32_16x16x32_f16(a1, b1v, acc11, 0, 0, 0);
    }
  }
  __syncthreads();   // all t_s reads done; u_s reusable as fp32

  // ---- write f2 to LDS (fp32, stride 132), D-layout
  {
    float* fs = (float*)u_s;
    int col0 = (tile0 << 4) + ln16, col1 = (tile1 << 4) + ln16;
    float bv0 = b2[col0], bv1 = b2[col1];
    #pragma unroll
    for (int r = 0; r < 4; r++){
      int m0 = (quad << 2) + r;
      fs[m0*132 + col0]        = gelu_f(acc00[r] + bv0);
      fs[m0*132 + col1]        = gelu_f(acc01[r] + bv1);
      fs[(m0 + 16)*132 + col0] = gelu_f(acc10[r] + bv0);
      fs[(m0 + 16)*132 + col1] = gelu_f(acc11[r] + bv1);
    }
  }
  __syncthreads();

  // ---- coalesced residual epilogue: out = nf + f2
  {
    const float* fs = (const float*)u_s;
    #pragma unroll
    for (int q = 0; q < 8; q++){
      int m = (w << 3) + q;
      float2 o;
      o.x = nfr[q].x + fs[m*132 + 2*l];
      o.y = nfr[q].y + fs[m*132 + 2*l + 1];
      *(float2*)&out[(size_t)(nb + m)*128 + 2*l] = o;
    }
  }
}

extern "C" void kernel_launch(void* const* d_in, const int* in_sizes, int n_in,
                              void* d_out, int out_size, void* d_ws, size_t ws_size,
                              hipStream_t stream) {
  const float* nf   = (const float*)d_in[0];
  const int*   ei   = (const int*)  d_in[1];
  const float* ln1g = (const float*)d_in[3];
  const float* ln1b = (const float*)d_in[4];
  const float* Wc   = (const float*)d_in[5];
  const float* bc   = (const float*)d_in[6];
  const float* ln2g = (const float*)d_in[7];
  const float* ln2b = (const float*)d_in[8];
  const float* W1   = (const float*)d_in[9];
  const float* b1   = (const float*)d_in[10];
  const float* W2   = (const float*)d_in[11];
  const float* b2   = (const float*)d_in[12];
  float* out = (float*)d_out;

  int N = in_sizes[0] / 128;
  int E = in_sizes[1] / 2;
  int NB  = (N + 63) >> 6;            // 1563
  int ESB = (E + SBLK - 1) / SBLK;    // 7813

  char* ws = (char*)d_ws;
  _Float16* hs   = (_Float16*)ws;                              // [N,128] f16
  _Float16* aggh = (_Float16*)(ws + (size_t)N*128*2);          // [N,128] f16
  char* p = ws + (size_t)N*128*4;
  p = (char*)(((size_t)p + 15) & ~(size_t)15);
  int*   cnt         = (int*)p;   p += (size_t)SBLK*NB*4;
  int*   total       = (int*)p;   p += (size_t)NB*4;
  int*   bucketStart = (int*)p;   p += (size_t)(NB+1)*4;
  float* dinv        = (float*)p; p += (size_t)N*4;
  int*   incount     = (int*)p;   p += (size_t)N*4;
  int*   row_start   = (int*)p;   p += (size_t)N*4;
  int*   eb          = (int*)p;   p += (size_t)E*4;
  int*   eSrc        = (int*)p;   p += (size_t)E*4;
  p = (char*)(((size_t)p + 15) & ~(size_t)15);
  _Float16* Wcp = (_Float16*)p; p += (size_t)2048*8*2;    // 32 KB
  _Float16* W1p = (_Float16*)p; p += (size_t)8192*8*2;    // 128 KB
  _Float16* W2p = (_Float16*)p; p += (size_t)8192*8*2;    // 128 KB

  k_hist   <<<SBLK, 256, 0, stream>>>(ei, cnt, E, NB, ESB);
  k_scanB  <<<NB, 128, 0, stream>>>(cnt, total, NB);
  k_scan2  <<<1, 256, 0, stream>>>(total, bucketStart, NB);
  k_scatter<<<SBLK, 256, 0, stream>>>(ei, cnt, bucketStart, eb, E, NB, ESB);
  k_sort2  <<<NB, 256, 0, stream>>>(eb, bucketStart, eSrc, row_start, incount, dinv, N);

  k_prep   <<<72 + N/4, 256, 0, stream>>>(Wc, W1, W2, Wcp, W1p, W2p, nf, ln1g, ln1b, dinv, hs);
  k_gather <<<N/4, 256, 0, stream>>>(hs, eSrc, row_start, incount, dinv, aggh, N);
  k_ffn    <<<N/32, 256, 0, stream>>>(nf, aggh, Wcp, bc, ln2g, ln2b, W1p, b1, W2p, b2, out, N);
}